// Round 1
// baseline (2290.453 us; speedup 1.0000x reference)
//
#include <hip/hip_runtime.h>
#include <math.h>

#define HID 64
#define TSTEPS 2048
#define CHUNK 32
#define EPSN 1e-5f

// ---------------------------------------------------------------------------
// Kernel 1: x = GELU(LayerNorm(ce @ w1 + b1))  -> written into d_out (staging)
// One wave (64 lanes) per row; lane c owns channel c. 4 rows per block.
// ---------------------------------------------------------------------------
__global__ void k_inproj(const float* __restrict__ ce, const float* __restrict__ w1,
                         const float* __restrict__ b1, const float* __restrict__ g1,
                         const float* __restrict__ be1, float* __restrict__ xout,
                         int nrows) {
    const int lane = threadIdx.x & 63;
    const int wave = threadIdx.x >> 6;
    const long row = (long)blockIdx.x * 4 + wave;
    if (row >= nrows) return;
    const float* cr = ce + row * 6;
    float acc = b1[lane];
    acc += cr[0] * w1[0 * HID + lane];
    acc += cr[1] * w1[1 * HID + lane];
    acc += cr[2] * w1[2 * HID + lane];
    acc += cr[3] * w1[3 * HID + lane];
    acc += cr[4] * w1[4 * HID + lane];
    acc += cr[5] * w1[5 * HID + lane];
    // LayerNorm across the 64 lanes (wave-wide shuffle reduction)
    float s = acc;
#pragma unroll
    for (int m = 32; m >= 1; m >>= 1) s += __shfl_xor(s, m, 64);
    const float mean = s * (1.0f / 64.0f);
    const float d = acc - mean;
    float q = d * d;
#pragma unroll
    for (int m = 32; m >= 1; m >>= 1) q += __shfl_xor(q, m, 64);
    const float var = q * (1.0f / 64.0f);
    const float xn = d * rsqrtf(var + EPSN) * g1[lane] + be1[lane];
    // exact (erf-based) GELU
    const float ge = 0.5f * xn * (1.0f + erff(xn * 0.70710678118654752440f));
    xout[row * HID + lane] = ge;
}

// ---------------------------------------------------------------------------
// Kernel 2: GRU scan + fused out-projection LayerNorm.
// grid = B (256) blocks, 256 threads (4 waves), 1 block per CU.
//   waves 0-2 (tid 0..191): thread g computes W_ih[g].x_t + W_hh[g].h  (regs)
//   wave  3  (tid 192..255): overlapped epilogue LN(h_{t-1} @ w2 + b2) -> out
//   phase B : wave 0 gate math + h update; waves 2-3 prefetch next x chunk.
// x aliases out (d_out): row r is read as x only at iters <= r, written at r+1.
// ---------------------------------------------------------------------------
__global__ __launch_bounds__(256, 1) void k_gru(
    float* xo,  // (B,T,64): read as x, overwritten with output (same buffer)
    const float* __restrict__ W_ih, const float* __restrict__ b_ih,
    const float* __restrict__ W_hh, const float* __restrict__ b_hh,
    const float* __restrict__ w2, const float* __restrict__ b2,
    const float* __restrict__ g2, const float* __restrict__ be2) {
    __shared__ __align__(16) float s_lds[192];   // r,z merged preacts; i_n in [128,192)
    __shared__ __align__(16) float hn_lds[64];   // h_n preact
    __shared__ __align__(16) float hbuf[64];     // h_{t-1}
    __shared__ float4 xbuf[2][CHUNK][16];        // double-buffered x chunks (16 KiB)

    const int tid = threadIdx.x;
    const int b = blockIdx.x;
    float* xb = xo + (long)b * TSTEPS * HID;

    // ---- per-thread weight registers ----
    float4 Wih[16], Whh[16];
    float bias_s = 0.0f, bi_n = 0.0f, bh_n = 0.0f;
    if (tid < 192) {
        const float4* wi = (const float4*)(W_ih + tid * HID);
        const float4* wh = (const float4*)(W_hh + tid * HID);
#pragma unroll
        for (int k = 0; k < 16; ++k) { Wih[k] = wi[k]; Whh[k] = wh[k]; }
        if (tid < 128) {
            bias_s = b_ih[tid] + b_hh[tid];
        } else {
            bi_n = b_ih[tid];
            bh_n = b_hh[tid];
        }
    }
    float4 w2c[16];
    float b2r = 0.0f, g2r = 0.0f, be2r = 0.0f;
    if (tid >= 192) {
        const int d = tid - 192;
#pragma unroll
        for (int k = 0; k < 16; ++k) {
            w2c[k] = make_float4(w2[(k * 4 + 0) * HID + d], w2[(k * 4 + 1) * HID + d],
                                 w2[(k * 4 + 2) * HID + d], w2[(k * 4 + 3) * HID + d]);
        }
        b2r = b2[d];
        g2r = g2[d];
        be2r = be2[d];
    }

    // ---- init h, load chunk 0 ----
    if (tid < 64) hbuf[tid] = 0.0f;
    {
        const float4* src = (const float4*)xb;  // rows 0..CHUNK-1 = 512 float4
        float4* dst = (float4*)xbuf[0];
#pragma unroll
        for (int j = 0; j < (CHUNK * 16) / 256; ++j) dst[tid + j * 256] = src[tid + j * 256];
    }
    float h_reg = 0.0f;
    __syncthreads();

    for (int t = 0; t <= TSTEPS; ++t) {
        // ---------------- phase A ----------------
        if (tid < 192) {
            if (t < TSTEPS) {
                const float4* xr = xbuf[(t >> 5) & 1][t & (CHUNK - 1)];
                const float4* hr = (const float4*)hbuf;
                float ai = 0.0f, ah = 0.0f;
#pragma unroll
                for (int k = 0; k < 16; ++k) {
                    const float4 xv = xr[k];
                    const float4 hv = hr[k];
                    const float4 wi = Wih[k];
                    const float4 wh = Whh[k];
                    ai += wi.x * xv.x + wi.y * xv.y + wi.z * xv.z + wi.w * xv.w;
                    ah += wh.x * hv.x + wh.y * hv.y + wh.z * hv.z + wh.w * hv.w;
                }
                if (tid < 128) {
                    s_lds[tid] = ai + ah + bias_s;
                } else {
                    s_lds[tid] = ai + bi_n;
                    hn_lds[tid - 128] = ah + bh_n;
                }
            }
        } else if (t > 0) {
            // overlapped epilogue for h_{t-1}
            const int d = tid - 192;
            const float4* hr = (const float4*)hbuf;
            float y = b2r;
#pragma unroll
            for (int k = 0; k < 16; ++k) {
                const float4 hv = hr[k];
                const float4 wv = w2c[k];
                y += wv.x * hv.x + wv.y * hv.y + wv.z * hv.z + wv.w * hv.w;
            }
            float s = y;
#pragma unroll
            for (int m = 32; m >= 1; m >>= 1) s += __shfl_xor(s, m, 64);
            const float mean = s * (1.0f / 64.0f);
            const float dd = y - mean;
            float q = dd * dd;
#pragma unroll
            for (int m = 32; m >= 1; m >>= 1) q += __shfl_xor(q, m, 64);
            const float var = q * (1.0f / 64.0f);
            xb[(long)(t - 1) * HID + d] = dd * rsqrtf(var + EPSN) * g2r + be2r;
        }
        __syncthreads();
        // ---------------- phase B ----------------
        if (t < TSTEPS) {
            if (tid < 64) {
                const float r = 1.0f / (1.0f + __expf(-s_lds[tid]));
                const float z = 1.0f / (1.0f + __expf(-s_lds[64 + tid]));
                const float pre = s_lds[128 + tid] + r * hn_lds[tid];
                const float e2 = __expf(2.0f * pre);
                const float n = 1.0f - 2.0f / (e2 + 1.0f);  // tanh, saturates cleanly
                h_reg = (1.0f - z) * n + z * h_reg;
                hbuf[tid] = h_reg;
            }
            const int tn = t + 1;
            if ((t & (CHUNK - 1)) == (CHUNK - 1) && tn < TSTEPS && tid >= 128) {
                const int j = tid - 128;  // 0..127; 512 float4 -> 4 each
                const float4* src = (const float4*)(xb + (long)tn * HID);
                float4* dst = (float4*)xbuf[(tn >> 5) & 1];
#pragma unroll
                for (int q2 = 0; q2 < 4; ++q2) dst[j + q2 * 128] = src[j + q2 * 128];
            }
        }
        __syncthreads();
    }
}

extern "C" void kernel_launch(void* const* d_in, const int* in_sizes, int n_in,
                              void* d_out, int out_size, void* d_ws, size_t ws_size,
                              hipStream_t stream) {
    const float* ce  = (const float*)d_in[0];
    const float* w1  = (const float*)d_in[1];
    const float* b1  = (const float*)d_in[2];
    const float* g1  = (const float*)d_in[3];
    const float* be1 = (const float*)d_in[4];
    const float* Wih = (const float*)d_in[5];
    const float* bih = (const float*)d_in[6];
    const float* Whh = (const float*)d_in[7];
    const float* bhh = (const float*)d_in[8];
    const float* w2  = (const float*)d_in[9];
    const float* b2  = (const float*)d_in[10];
    const float* g2  = (const float*)d_in[11];
    const float* be2 = (const float*)d_in[12];
    float* out = (float*)d_out;

    const int nrows = in_sizes[0] / 6;       // B*T
    const int B = nrows / TSTEPS;            // 256

    // Stage x = GELU(LN(ce@w1+b1)) directly into d_out; k_gru consumes it and
    // overwrites each row with the final output strictly after its last read.
    k_inproj<<<(nrows + 3) / 4, 256, 0, stream>>>(ce, w1, b1, g1, be1, out, nrows);
    k_gru<<<B, 256, 0, stream>>>(out, Wih, bih, Whh, bhh, w2, b2, g2, be2);
}

// Round 2
// 2277.851 us; speedup vs baseline: 1.0055x; 1.0055x over previous
//
#include <hip/hip_runtime.h>
#include <math.h>

#define HID 64
#define TST 2048
#define CH 16              // timesteps per chunk
#define NCH (TST / CH)     // 128 chunks
#define EPSN 1e-5f

typedef float v2f __attribute__((ext_vector_type(2)));

// ---------------------------------------------------------------------------
// Kernel 1: x = GELU(LayerNorm(ce @ w1 + b1))  -> staged into d_out
// One wave per row, lane c owns channel c; 4 rows per 256-thread block.
// ---------------------------------------------------------------------------
__global__ void k_inproj(const float* __restrict__ ce, const float* __restrict__ w1,
                         const float* __restrict__ b1, const float* __restrict__ g1,
                         const float* __restrict__ be1, float* __restrict__ xout,
                         int nrows) {
    const int lane = threadIdx.x & 63;
    const int wave = threadIdx.x >> 6;
    const long row = (long)blockIdx.x * 4 + wave;
    if (row >= nrows) return;
    const float* cr = ce + row * 6;
    float acc = b1[lane];
    acc += cr[0] * w1[0 * HID + lane];
    acc += cr[1] * w1[1 * HID + lane];
    acc += cr[2] * w1[2 * HID + lane];
    acc += cr[3] * w1[3 * HID + lane];
    acc += cr[4] * w1[4 * HID + lane];
    acc += cr[5] * w1[5 * HID + lane];
    float s = acc;
#pragma unroll
    for (int m = 32; m >= 1; m >>= 1) s += __shfl_xor(s, m, 64);
    const float mean = s * (1.0f / 64.0f);
    const float d = acc - mean;
    float q = d * d;
#pragma unroll
    for (int m = 32; m >= 1; m >>= 1) q += __shfl_xor(q, m, 64);
    const float var = q * (1.0f / 64.0f);
    const float xn = d * rsqrtf(var + EPSN) * g1[lane] + be1[lane];
    const float ge = 0.5f * xn * (1.0f + erff(xn * 0.70710678118654752440f));
    xout[row * HID + lane] = ge;
}

// ---------------------------------------------------------------------------
// Kernel 2: GRU scan with single-wave recurrence (no per-step barriers).
//   wave 0: the scan. lane j holds W_hh rows j / 64+j / 128+j in registers
//           (192 VGPRs as float2 -> v_pk_fma_f32). h round-trips through LDS
//           within the wave only.
//   waves 1-2: gi = W_ih.x + b_ih for chunk p (one chunk ahead of the scan),
//           into double-buffered gibuf.
//   wave 3: LN(h@w2+b2) epilogue for chunk p-2 (reads hist) + x prefetch.
//   __syncthreads only at chunk boundaries (NCH+2 total).
// x aliases d_out: row r is read (prefetch) at p=r/CH-1, written at p=r/CH+2.
// ---------------------------------------------------------------------------
__global__ __launch_bounds__(256, 1)
__attribute__((amdgpu_waves_per_eu(1, 1)))
void k_gru(float* xo,
           const float* __restrict__ W_ih, const float* __restrict__ b_ih,
           const float* __restrict__ W_hh, const float* __restrict__ b_hh,
           const float* __restrict__ w2, const float* __restrict__ b2,
           const float* __restrict__ g2, const float* __restrict__ be2) {
    __shared__ __align__(16) float4 xbuf[2][CH][16];    // 8 KB  x chunks
    __shared__ __align__(16) float gibuf[2][CH][192];   // 24 KB gi preacts
    __shared__ __align__(16) float hist[2][CH][HID];    // 8 KB  h history
    __shared__ __align__(16) float hbuf[HID];           // h broadcast (wave 0 only)

    const int tid = threadIdx.x;
    const int lane = tid & 63;
    const int wv = tid >> 6;
    float* xb = xo + (size_t)blockIdx.x * TST * HID;

    // ---- per-role register state ----
    v2f wr[32], wz[32], wn[32];          // wave 0: W_hh rows (192 regs)
    float bhr = 0.f, bhz = 0.f, bhn = 0.f;
    v2f wiA[32], wiB[32];                // waves 1-2: W_ih rows
    float biA = 0.f, biB = 0.f;
    v2f w2v[32];                         // wave 3: w2 column
    float b2r = 0.f, g2r = 0.f, be2r = 0.f;

    if (wv == 0) {
        const v2f* r0 = (const v2f*)(W_hh + (size_t)lane * HID);
        const v2f* r1 = (const v2f*)(W_hh + (size_t)(64 + lane) * HID);
        const v2f* r2 = (const v2f*)(W_hh + (size_t)(128 + lane) * HID);
#pragma unroll
        for (int k = 0; k < 32; ++k) { wr[k] = r0[k]; wz[k] = r1[k]; wn[k] = r2[k]; }
        bhr = b_hh[lane]; bhz = b_hh[64 + lane]; bhn = b_hh[128 + lane];
        hbuf[lane] = 0.0f;
    } else if (wv == 1) {
        const v2f* rA = (const v2f*)(W_ih + (size_t)lane * HID);
        const v2f* rB = (const v2f*)(W_ih + (size_t)(128 + lane) * HID);
#pragma unroll
        for (int k = 0; k < 32; ++k) { wiA[k] = rA[k]; wiB[k] = rB[k]; }
        biA = b_ih[lane]; biB = b_ih[128 + lane];
    } else if (wv == 2) {
        const v2f* rA = (const v2f*)(W_ih + (size_t)(64 + lane) * HID);
#pragma unroll
        for (int k = 0; k < 32; ++k) { wiA[k] = rA[k]; }
        biA = b_ih[64 + lane];
    } else {
#pragma unroll
        for (int k = 0; k < 32; ++k) {
            w2v[k].x = w2[(size_t)(2 * k) * HID + lane];
            w2v[k].y = w2[(size_t)(2 * k + 1) * HID + lane];
        }
        b2r = b2[lane]; g2r = g2[lane]; be2r = be2[lane];
    }

    // ---- prologue: stage x chunk 0 ----
    {
        const float4* src = (const float4*)xb;          // rows 0..CH-1 = 256 float4
        ((float4*)xbuf[0])[tid] = src[tid];
    }
    float h_reg = 0.0f;
    __syncthreads();

    // ---- main loop over phases ----
    // phase p: gi(chunk p) | scan(chunk p-1) | epilogue(chunk p-2) | prefetch x(p+1)
    for (int p = 0; p <= NCH + 1; ++p) {
        if (wv == 0) {
            if (p >= 1 && p <= NCH) {
                const int c = p - 1;
                const float* gp = (const float*)gibuf[c & 1];
                float* hp = (float*)hist[c & 1];
                for (int t = 0; t < CH; ++t) {
                    const float gr = gp[t * 192 + lane];
                    const float gz = gp[t * 192 + 64 + lane];
                    const float gn = gp[t * 192 + 128 + lane];
                    const v2f* hv = (const v2f*)hbuf;
                    v2f ar = {0.f, 0.f}, az = {0.f, 0.f}, an = {0.f, 0.f};
#pragma unroll
                    for (int k = 0; k < 32; ++k) {
                        const v2f h2 = hv[k];
                        ar += wr[k] * h2;
                        az += wz[k] * h2;
                        an += wn[k] * h2;
                    }
                    const float rpre = gr + ar.x + ar.y + bhr;
                    const float zpre = gz + az.x + az.y + bhz;
                    const float hn = an.x + an.y + bhn;
                    const float r = 1.0f / (1.0f + __expf(-rpre));
                    const float z = 1.0f / (1.0f + __expf(-zpre));
                    const float pre = gn + r * hn;
                    const float e2 = __expf(2.0f * pre);
                    const float n = 1.0f - 2.0f / (e2 + 1.0f);
                    h_reg = (1.0f - z) * n + z * h_reg;
                    hbuf[lane] = h_reg;
                    hp[t * HID + lane] = h_reg;
                }
            }
        } else if (wv == 1 || wv == 2) {
            if (p < NCH) {
                const float4* xc = (const float4*)xbuf[p & 1];
                float* gp = (float*)gibuf[p & 1];
                for (int t = 0; t < CH; ++t) {
                    const v2f* xv = (const v2f*)(xc + t * 16);
                    v2f aA = {0.f, 0.f}, aB = {0.f, 0.f};
                    if (wv == 1) {
#pragma unroll
                        for (int k = 0; k < 32; ++k) {
                            const v2f x2 = xv[k];
                            aA += wiA[k] * x2;
                            aB += wiB[k] * x2;
                        }
                        gp[t * 192 + lane] = aA.x + aA.y + biA;
                        gp[t * 192 + 128 + lane] = aB.x + aB.y + biB;
                    } else {
#pragma unroll
                        for (int k = 0; k < 32; ++k) {
                            const v2f x2 = xv[k];
                            aA += wiA[k] * x2;
                        }
                        gp[t * 192 + 64 + lane] = aA.x + aA.y + biA;
                    }
                }
            }
        } else {
            // epilogue for chunk p-2
            if (p >= 2) {
                const int ce = p - 2;
                const float* hp = (const float*)hist[ce & 1];
                for (int t = 0; t < CH; ++t) {
                    const v2f* hr = (const v2f*)(hp + t * HID);
                    v2f a2 = {0.f, 0.f};
#pragma unroll
                    for (int k = 0; k < 32; ++k) a2 += w2v[k] * hr[k];
                    const float y = b2r + a2.x + a2.y;
                    float s = y;
#pragma unroll
                    for (int m = 32; m >= 1; m >>= 1) s += __shfl_xor(s, m, 64);
                    const float mean = s * (1.0f / 64.0f);
                    const float dd = y - mean;
                    float q = dd * dd;
#pragma unroll
                    for (int m = 32; m >= 1; m >>= 1) q += __shfl_xor(q, m, 64);
                    const float var = q * (1.0f / 64.0f);
                    xb[(size_t)(ce * CH + t) * HID + lane] =
                        dd * rsqrtf(var + EPSN) * g2r + be2r;
                }
            }
            // prefetch x chunk p+1
            if (p + 1 < NCH) {
                const float4* src = (const float4*)(xb + (size_t)(p + 1) * CH * HID);
                float4* dst = (float4*)xbuf[(p + 1) & 1];
#pragma unroll
                for (int q2 = 0; q2 < 4; ++q2) dst[lane + q2 * 64] = src[lane + q2 * 64];
            }
        }
        __syncthreads();
    }
}

extern "C" void kernel_launch(void* const* d_in, const int* in_sizes, int n_in,
                              void* d_out, int out_size, void* d_ws, size_t ws_size,
                              hipStream_t stream) {
    const float* ce  = (const float*)d_in[0];
    const float* w1  = (const float*)d_in[1];
    const float* b1  = (const float*)d_in[2];
    const float* g1  = (const float*)d_in[3];
    const float* be1 = (const float*)d_in[4];
    const float* Wih = (const float*)d_in[5];
    const float* bih = (const float*)d_in[6];
    const float* Whh = (const float*)d_in[7];
    const float* bhh = (const float*)d_in[8];
    const float* w2  = (const float*)d_in[9];
    const float* b2  = (const float*)d_in[10];
    const float* g2  = (const float*)d_in[11];
    const float* be2 = (const float*)d_in[12];
    float* out = (float*)d_out;

    const int nrows = in_sizes[0] / 6;   // B*T
    const int B = nrows / TST;           // 256

    k_inproj<<<(nrows + 3) / 4, 256, 0, stream>>>(ce, w1, b1, g1, be1, out, nrows);
    k_gru<<<B, 256, 0, stream>>>(out, Wih, bih, Whh, bhh, w2, b2, g2, be2);
}

// Round 3
// 1990.239 us; speedup vs baseline: 1.1508x; 1.1445x over previous
//
#include <hip/hip_runtime.h>
#include <math.h>

#define HID 64
#define TST 2048
#define CH 16              // timesteps per chunk
#define NCH (TST / CH)     // 128 chunks
#define EPSN 1e-5f

typedef float v2f __attribute__((ext_vector_type(2)));

// ---------------------------------------------------------------------------
// Kernel 1: x = GELU(LayerNorm(ce @ w1 + b1))  -> staged into d_out
// ---------------------------------------------------------------------------
__global__ void k_inproj(const float* __restrict__ ce, const float* __restrict__ w1,
                         const float* __restrict__ b1, const float* __restrict__ g1,
                         const float* __restrict__ be1, float* __restrict__ xout,
                         int nrows) {
    const int lane = threadIdx.x & 63;
    const int wave = threadIdx.x >> 6;
    const long row = (long)blockIdx.x * 4 + wave;
    if (row >= nrows) return;
    const float* cr = ce + row * 6;
    float acc = b1[lane];
    acc += cr[0] * w1[0 * HID + lane];
    acc += cr[1] * w1[1 * HID + lane];
    acc += cr[2] * w1[2 * HID + lane];
    acc += cr[3] * w1[3 * HID + lane];
    acc += cr[4] * w1[4 * HID + lane];
    acc += cr[5] * w1[5 * HID + lane];
    float s = acc;
#pragma unroll
    for (int m = 32; m >= 1; m >>= 1) s += __shfl_xor(s, m, 64);
    const float mean = s * (1.0f / 64.0f);
    const float d = acc - mean;
    float q = d * d;
#pragma unroll
    for (int m = 32; m >= 1; m >>= 1) q += __shfl_xor(q, m, 64);
    const float var = q * (1.0f / 64.0f);
    const float xn = d * rsqrtf(var + EPSN) * g1[lane] + be1[lane];
    const float ge = 0.5f * xn * (1.0f + erff(xn * 0.70710678118654752440f));
    xout[row * HID + lane] = ge;
}

// ---------------------------------------------------------------------------
// Kernel 2: GRU scan, wave-specialized, chunk-phased.
//   wave 0: serial scan (W_hh in 192 VGPRs), h via LDS broadcast, no barriers
//           inside a chunk.
//   waves 1-2: gi = W_ih.x + b_ih for chunk p (one ahead), double-buffered.
//   wave 3: LN(h@w2+b2) epilogue for chunk p-2 with PIPELINED moment
//           reductions (32 independent shuffle streams, latency overlapped),
//           then x prefetch for chunk p+1.
// ---------------------------------------------------------------------------
__global__ __launch_bounds__(256, 1)
__attribute__((amdgpu_waves_per_eu(1, 1)))
void k_gru(float* xo,
           const float* __restrict__ W_ih, const float* __restrict__ b_ih,
           const float* __restrict__ W_hh, const float* __restrict__ b_hh,
           const float* __restrict__ w2, const float* __restrict__ b2,
           const float* __restrict__ g2, const float* __restrict__ be2) {
    __shared__ __align__(16) float4 xbuf[2][CH][16];    // 8 KB  x chunks
    __shared__ __align__(16) float gibuf[2][CH][192];   // 24 KB gi preacts
    __shared__ __align__(16) float hist[2][CH][HID];    // 8 KB  h history
    __shared__ __align__(16) float hbuf[HID];           // h broadcast (wave 0)

    const int tid = threadIdx.x;
    const int lane = tid & 63;
    const int wv = tid >> 6;
    float* xb = xo + (size_t)blockIdx.x * TST * HID;

    v2f wr[32], wz[32], wn[32];          // wave 0: W_hh rows
    float bhr = 0.f, bhz = 0.f, bhn = 0.f;
    v2f wiA[32], wiB[32];                // waves 1-2: W_ih rows
    float biA = 0.f, biB = 0.f;
    v2f w2v[32];                         // wave 3: w2 column
    float b2r = 0.f, g2r = 0.f, be2r = 0.f;

    if (wv == 0) {
        const v2f* r0 = (const v2f*)(W_hh + (size_t)lane * HID);
        const v2f* r1 = (const v2f*)(W_hh + (size_t)(64 + lane) * HID);
        const v2f* r2 = (const v2f*)(W_hh + (size_t)(128 + lane) * HID);
#pragma unroll
        for (int k = 0; k < 32; ++k) { wr[k] = r0[k]; wz[k] = r1[k]; wn[k] = r2[k]; }
        bhr = b_hh[lane]; bhz = b_hh[64 + lane]; bhn = b_hh[128 + lane];
        hbuf[lane] = 0.0f;
    } else if (wv == 1) {
        const v2f* rA = (const v2f*)(W_ih + (size_t)lane * HID);
        const v2f* rB = (const v2f*)(W_ih + (size_t)(128 + lane) * HID);
#pragma unroll
        for (int k = 0; k < 32; ++k) { wiA[k] = rA[k]; wiB[k] = rB[k]; }
        biA = b_ih[lane]; biB = b_ih[128 + lane];
    } else if (wv == 2) {
        const v2f* rA = (const v2f*)(W_ih + (size_t)(64 + lane) * HID);
#pragma unroll
        for (int k = 0; k < 32; ++k) { wiA[k] = rA[k]; }
        biA = b_ih[64 + lane];
    } else {
#pragma unroll
        for (int k = 0; k < 32; ++k) {
            w2v[k].x = w2[(size_t)(2 * k) * HID + lane];
            w2v[k].y = w2[(size_t)(2 * k + 1) * HID + lane];
        }
        b2r = b2[lane]; g2r = g2[lane]; be2r = be2[lane];
    }

    {
        const float4* src = (const float4*)xb;
        ((float4*)xbuf[0])[tid] = src[tid];
    }
    float h_reg = 0.0f;
    __syncthreads();

    for (int p = 0; p <= NCH + 1; ++p) {
        if (wv == 0) {
            if (p >= 1 && p <= NCH) {
                const int c = p - 1;
                const float* gp = (const float*)gibuf[c & 1];
                float* hp = (float*)hist[c & 1];
                for (int t = 0; t < CH; ++t) {
                    const float gr = gp[t * 192 + lane];
                    const float gz = gp[t * 192 + 64 + lane];
                    const float gn = gp[t * 192 + 128 + lane];
                    const v2f* hv = (const v2f*)hbuf;
                    v2f ar = {0.f, 0.f}, az = {0.f, 0.f}, an = {0.f, 0.f};
#pragma unroll
                    for (int k = 0; k < 32; ++k) {
                        const v2f h2 = hv[k];
                        ar += wr[k] * h2;
                        az += wz[k] * h2;
                        an += wn[k] * h2;
                    }
                    const float rpre = gr + ar.x + ar.y + bhr;
                    const float zpre = gz + az.x + az.y + bhz;
                    const float hn = an.x + an.y + bhn;
                    const float r = 1.0f / (1.0f + __expf(-rpre));
                    const float z = 1.0f / (1.0f + __expf(-zpre));
                    const float pre = gn + r * hn;
                    const float e2 = __expf(2.0f * pre);
                    const float n = 1.0f - 2.0f / (e2 + 1.0f);
                    h_reg = (1.0f - z) * n + z * h_reg;
                    hbuf[lane] = h_reg;
                    hp[t * HID + lane] = h_reg;
                }
            }
        } else if (wv == 1 || wv == 2) {
            if (p < NCH) {
                const float4* xc = (const float4*)xbuf[p & 1];
                float* gp = (float*)gibuf[p & 1];
                for (int t = 0; t < CH; ++t) {
                    const v2f* xv = (const v2f*)(xc + t * 16);
                    v2f aA = {0.f, 0.f}, aB = {0.f, 0.f};
                    if (wv == 1) {
#pragma unroll
                        for (int k = 0; k < 32; ++k) {
                            const v2f x2 = xv[k];
                            aA += wiA[k] * x2;
                            aB += wiB[k] * x2;
                        }
                        gp[t * 192 + lane] = aA.x + aA.y + biA;
                        gp[t * 192 + 128 + lane] = aB.x + aB.y + biB;
                    } else {
#pragma unroll
                        for (int k = 0; k < 32; ++k) {
                            const v2f x2 = xv[k];
                            aA += wiA[k] * x2;
                        }
                        gp[t * 192 + 64 + lane] = aA.x + aA.y + biA;
                    }
                }
            }
        } else {
            // ---- epilogue for chunk p-2: pipelined LN over 16 timesteps ----
            if (p >= 2) {
                const int ce = p - 2;
                const float* hp = (const float*)hist[ce & 1];
                float yv[CH];
#pragma unroll
                for (int t = 0; t < CH; ++t) {
                    const v2f* hr = (const v2f*)(hp + t * HID);
                    v2f a2 = {0.f, 0.f};
#pragma unroll
                    for (int k = 0; k < 32; ++k) a2 += w2v[k] * hr[k];
                    yv[t] = b2r + a2.x + a2.y;
                }
                float sv[CH], qv[CH];
#pragma unroll
                for (int t = 0; t < CH; ++t) { sv[t] = yv[t]; qv[t] = yv[t] * yv[t]; }
                // 32 independent shuffle streams per level -> latency overlaps
#pragma unroll
                for (int m = 32; m >= 1; m >>= 1) {
#pragma unroll
                    for (int t = 0; t < CH; ++t) sv[t] += __shfl_xor(sv[t], m, 64);
#pragma unroll
                    for (int t = 0; t < CH; ++t) qv[t] += __shfl_xor(qv[t], m, 64);
                }
#pragma unroll
                for (int t = 0; t < CH; ++t) {
                    const float mean = sv[t] * (1.0f / 64.0f);
                    const float var = qv[t] * (1.0f / 64.0f) - mean * mean;
                    const float dd = yv[t] - mean;
                    xb[(size_t)(ce * CH + t) * HID + lane] =
                        dd * rsqrtf(var + EPSN) * g2r + be2r;
                }
            }
            // prefetch x chunk p+1
            if (p + 1 < NCH) {
                const float4* src = (const float4*)(xb + (size_t)(p + 1) * CH * HID);
                float4* dst = (float4*)xbuf[(p + 1) & 1];
#pragma unroll
                for (int q2 = 0; q2 < 4; ++q2) dst[lane + q2 * 64] = src[lane + q2 * 64];
            }
        }
        __syncthreads();
    }
}

extern "C" void kernel_launch(void* const* d_in, const int* in_sizes, int n_in,
                              void* d_out, int out_size, void* d_ws, size_t ws_size,
                              hipStream_t stream) {
    const float* ce  = (const float*)d_in[0];
    const float* w1  = (const float*)d_in[1];
    const float* b1  = (const float*)d_in[2];
    const float* g1  = (const float*)d_in[3];
    const float* be1 = (const float*)d_in[4];
    const float* Wih = (const float*)d_in[5];
    const float* bih = (const float*)d_in[6];
    const float* Whh = (const float*)d_in[7];
    const float* bhh = (const float*)d_in[8];
    const float* w2  = (const float*)d_in[9];
    const float* b2  = (const float*)d_in[10];
    const float* g2  = (const float*)d_in[11];
    const float* be2 = (const float*)d_in[12];
    float* out = (float*)d_out;

    const int nrows = in_sizes[0] / 6;   // B*T
    const int B = nrows / TST;           // 256

    k_inproj<<<(nrows + 3) / 4, 256, 0, stream>>>(ce, w1, b1, g1, be1, out, nrows);
    k_gru<<<B, 256, 0, stream>>>(out, Wih, bih, Whh, bhh, w2, b2, g2, be2);
}